// Round 1
// baseline (4598.658 us; speedup 1.0000x reference)
//
#include <hip/hip_runtime.h>

typedef unsigned int uint;
typedef unsigned short ushort;

#define NLAT 361
#define NLON 720
#define NNZT 65536
#define CIN 64
#define COUT 64
#define NK 9
#define PADL 784     // 720 + 64 wrap pad
#define ROWCAP 512
#define CKTOT 576    // CIN*NK

__device__ __forceinline__ float bfu(uint u){ return __uint_as_float(u<<16); }
__device__ __forceinline__ float bfh(uint u){ return __uint_as_float(u & 0xffff0000u); }
__device__ __forceinline__ ushort f2bf(float f){
  uint b = __float_as_uint(f);
  return (ushort)((b + 0x7fffu + ((b>>16)&1u)) >> 16);
}
__device__ __forceinline__ uint packbf2(float f0, float f1){
  uint b0 = __float_as_uint(f0), b1 = __float_as_uint(f1);
  uint r0 = (b0 + 0x7fffu + ((b0>>16)&1u)) >> 16;
  uint r1 = ((b1 + 0x7fffu + ((b1>>16)&1u)) >> 16) << 16;
  return r0 | r1;
}

// ---------------- CSR build: per-row, k-sorted, deterministic ----------------
__global__ __launch_bounds__(256) void k_csr(const int* __restrict__ ker, const int* __restrict__ row,
                                             const int* __restrict__ col, const float* __restrict__ vals,
                                             int2* __restrict__ meta_g, int* __restrict__ kptr_g){
  const int lo = blockIdx.x, tid = threadIdx.x;
  __shared__ int cnt2[256*NK];
  #pragma unroll
  for (int kk=0;kk<NK;kk++) cnt2[tid*NK+kk]=0;
  __syncthreads();
  for (int i=tid;i<NNZT;i+=256) if (row[i]==lo) cnt2[tid*NK + ker[i]]++;
  __syncthreads();
  if (tid==0){
    int run=0;
    for (int kk=0;kk<NK;kk++){
      kptr_g[lo*10+kk]=run;
      for (int t=0;t<256;t++){ int tmp=cnt2[t*NK+kk]; cnt2[t*NK+kk]=run; run+=tmp; }
    }
    kptr_g[lo*10+9]=run;
  }
  __syncthreads();
  for (int i=tid;i<NNZT;i+=256) if (row[i]==lo){
    int kk=ker[i];
    int off=cnt2[tid*NK+kk]++;
    if (off<ROWCAP){
      int c=col[i];
      meta_g[lo*ROWCAP+off]=make_int2(((c/NLON)<<16)|(c%NLON), __float_as_int(vals[i]));
    }
  }
}

// ------------- x -> bf16, layout [b][lat][cpair(32)][784][2], wrap-padded ----
__global__ __launch_bounds__(256) void k_xb(const float* __restrict__ x, ushort* __restrict__ xb){
  const int bid=blockIdx.x, tid=threadIdx.x;
  const int b=bid/NLAT, lat=bid-b*NLAT;
  const float* xs = x + (size_t)b*CIN*NLAT*NLON + (size_t)lat*NLON;
  ushort* xd = xb + (size_t)(b*NLAT+lat)*32*PADL*2;
  for (int idx=tid; idx<CIN*PADL; idx+=256){
    int c=idx/PADL, j=idx-c*PADL;
    int jj = (j<NLON)? j : j-NLON;
    float v = xs[(size_t)c*NLAT*NLON + jj];
    xd[((c>>1)*PADL + j)*2 + (c&1)] = f2bf(v);
  }
}

// ---------------- fused gather + channel-mix main kernel ---------------------
template<int USE_XB>
__global__ __launch_bounds__(256,3) void k_main(const float* __restrict__ x, const ushort* __restrict__ xb,
    const int2* __restrict__ meta_g, const int* __restrict__ kptr_g,
    const float* __restrict__ w, const float* __restrict__ bias, float* __restrict__ out){
  const int bid=blockIdx.x, tid=threadIdx.x;
  const int lo=bid/6; const int rem=bid-lo*6;
  const int b=rem/3, pq=rem-(rem/3)*3;

  __shared__ int2  meta[ROWCAP];                 // 4 KB
  __shared__ __align__(16) ushort Ych[144*68];   // 19.6 KB, row stride 68 (pad)
  __shared__ uint  Wp[32*146];                   // 18.7 KB, oc-pairs packed bf16x2

  int kp[10];
  #pragma unroll
  for (int kk=0;kk<10;kk++){ int v=kptr_g[lo*10+kk]; kp[kk]=v<ROWCAP?v:ROWCAP; }
  for (int i=tid;i<kp[9];i+=256) meta[i]=meta_g[lo*ROWCAP+i];

  const int cg=tid>>6, pl=tid&63;      // gather roles: wave id (c-group), p-lane
  const int ocq=tid>>4, pq4=tid&15;    // stage-2 roles: oc-quad, p-quad
  float outacc[4][4][4];
  #pragma unroll
  for (int a=0;a<4;a++){
    #pragma unroll
    for (int b2=0;b2<4;b2++){
      #pragma unroll
      for (int c2=0;c2<4;c2++) outacc[a][b2][c2]=0.f;
    }
  }

  for (int chunk=0;chunk<4;chunk++){
    const int c0=chunk*16;
    __syncthreads();   // previous chunk's stage-2 done (Wp free); also covers meta on iter 0
    // load W chunk, packed as bf16 oc-pairs: Wp[oc2][ckl]
    for (int idx=tid; idx<32*144; idx+=256){
      int oc2=idx/144, ckl=idx-oc2*144;
      int cl=ckl/9, kk=ckl-cl*9;
      const float* wp = w + (oc2*2)*CKTOT + (c0+cl)*NK + kk;
      Wp[oc2*146+ckl] = packbf2(wp[0], wp[CKTOT]);
    }
    #pragma unroll
    for (int pt=0;pt<4;pt++){
      const int p0 = pq*240 + pt*64;
      float acc[4][NK];
      #pragma unroll
      for (int j=0;j<4;j++){
        #pragma unroll
        for (int kk=0;kk<NK;kk++) acc[j][kk]=0.f;
      }
      // ---- gather: k loop unrolled so acc index is static (no scratch) ----
      #pragma unroll
      for (int kk=0;kk<NK;kk++){
        for (int i=kp[kk]; i<kp[kk+1]; i++){
          int2 m=meta[i];
          int lat=m.x>>16, lon=m.x&0xffff;
          float v=__int_as_float(m.y);
          int s=lon+p0; s = (s>=NLON)? s-NLON : s;
          if (USE_XB){
            // bf16 pair layout: coalesced 256B/wave, 2 channels per dword
            int base=(((b*NLAT+lat)*32 + chunk*8 + cg)*PADL + s + pl)*2;
            uint u0=*(const uint*)(xb+base);
            uint u1=*(const uint*)(xb+base+8*PADL);
            acc[0][kk] += v*bfu(u0); acc[1][kk] += v*bfh(u0);
            acc[2][kk] += v*bfu(u1); acc[3][kk] += v*bfh(u1);
          } else {
            int widx=s+pl; widx = (widx>=NLON)? widx-NLON : widx;
            int base=((b*CIN + c0+cg)*NLAT + lat)*NLON + widx;
            acc[0][kk] += v*x[base];
            acc[1][kk] += v*x[base+4*NLAT*NLON];
            acc[2][kk] += v*x[base+8*NLAT*NLON];
            acc[3][kk] += v*x[base+12*NLAT*NLON];
          }
        }
      }
      __syncthreads();  // previous pt's stage-2 finished reading Ych
      #pragma unroll
      for (int j=0;j<4;j++){
        int cl = USE_XB ? (2*cg + (j&1) + (j>>1)*8) : (cg + 4*j);
        #pragma unroll
        for (int kk=0;kk<NK;kk++)
          Ych[(cl*NK+kk)*68 + pl] = f2bf(acc[j][kk]);
      }
      __syncthreads();  // Ych (and Wp) visible
      // ---- stage 2: out[oc][p] += W[oc][ck] * Y[ck][p], 4x4 reg blocking ----
      for (int ckl=0; ckl<144; ckl++){
        uint2 yy = *(const uint2*)&Ych[ckl*68 + pq4*4];
        uint w01 = Wp[(ocq*2)*146 + ckl];
        uint w23 = Wp[(ocq*2+1)*146 + ckl];
        float yf[4]={bfu(yy.x),bfh(yy.x),bfu(yy.y),bfh(yy.y)};
        float wf[4]={bfu(w01),bfh(w01),bfu(w23),bfh(w23)};
        #pragma unroll
        for (int jo=0;jo<4;jo++){
          #pragma unroll
          for (int jp=0;jp<4;jp++)
            outacc[pt][jo][jp] += wf[jo]*yf[jp];
        }
      }
    }
  }
  // ---- epilogue: coalesced float4 stores + bias ----
  #pragma unroll
  for (int pt=0;pt<4;pt++){
    int pidx = pt*64 + pq4*4;
    if (pidx<240){
      #pragma unroll
      for (int jo=0;jo<4;jo++){
        int oc=ocq*4+jo;
        float bs=bias[oc];
        float4 o4 = make_float4(outacc[pt][jo][0]+bs, outacc[pt][jo][1]+bs,
                                outacc[pt][jo][2]+bs, outacc[pt][jo][3]+bs);
        *(float4*)(out + ((size_t)(b*COUT+oc)*NLAT + lo)*NLON + pq*240 + pidx) = o4;
      }
    }
  }
}

extern "C" void kernel_launch(void* const* d_in, const int* in_sizes, int n_in,
                              void* d_out, int out_size, void* d_ws, size_t ws_size,
                              hipStream_t stream){
  const float* x   =(const float*)d_in[0];
  const float* vals=(const float*)d_in[1];
  const float* w   =(const float*)d_in[2];
  const float* bias=(const float*)d_in[3];
  const int* ker=(const int*)d_in[4];
  const int* row=(const int*)d_in[5];
  const int* col=(const int*)d_in[6];
  float* out=(float*)d_out;

  const size_t META_B=(size_t)NLAT*ROWCAP*sizeof(int2);
  const size_t KPTR_B=((size_t)NLAT*10*sizeof(int)+15)&~(size_t)15;
  const size_t XB_B=(size_t)2*NLAT*32*PADL*2*sizeof(ushort);
  int2* meta_g=(int2*)d_ws;
  int*  kptr_g=(int*)((char*)d_ws+META_B);
  ushort* xb=(ushort*)((char*)d_ws+META_B+KPTR_B);
  const bool use_xb = ws_size >= META_B+KPTR_B+XB_B;

  k_csr<<<dim3(NLAT), dim3(256), 0, stream>>>(ker,row,col,vals,meta_g,kptr_g);
  if (use_xb){
    k_xb<<<dim3(2*NLAT), dim3(256), 0, stream>>>(x, xb);
    k_main<1><<<dim3(NLAT*6), dim3(256), 0, stream>>>(x,xb,meta_g,kptr_g,w,bias,out);
  } else {
    k_main<0><<<dim3(NLAT*6), dim3(256), 0, stream>>>(x,xb,meta_g,kptr_g,w,bias,out);
  }
}

// Round 2
// 2682.403 us; speedup vs baseline: 1.7144x; 1.7144x over previous
//
#include <hip/hip_runtime.h>

typedef unsigned int uint;
typedef unsigned short ushort;

#define NLAT 361
#define NLON 720
#define NNZT 65536
#define CIN 64
#define COUT 64
#define NK 9
#define PADL 784     // 720 + 64 wrap pad
#define ROWCAP 384   // max row population ~230 (15 sigma margin)
#define CKTOT 576    // CIN*NK

__device__ __forceinline__ float bfu(uint u){ return __uint_as_float(u<<16); }
__device__ __forceinline__ float bfh(uint u){ return __uint_as_float(u & 0xffff0000u); }
__device__ __forceinline__ ushort f2bf(float f){
  uint b = __float_as_uint(f);
  return (ushort)((b + 0x7fffu + ((b>>16)&1u)) >> 16);
}
__device__ __forceinline__ uint packbf2(float f0, float f1){
  uint b0 = __float_as_uint(f0), b1 = __float_as_uint(f1);
  uint r0 = (b0 + 0x7fffu + ((b0>>16)&1u)) >> 16;
  uint r1 = ((b1 + 0x7fffu + ((b1>>16)&1u)) >> 16) << 16;
  return r0 | r1;
}

// ---------------- CSR build: per-row, k-sorted, deterministic ----------------
__global__ __launch_bounds__(256) void k_csr(const int* __restrict__ ker, const int* __restrict__ row,
                                             const int* __restrict__ col, const float* __restrict__ vals,
                                             int2* __restrict__ meta_g, int* __restrict__ kptr_g){
  const int lo = blockIdx.x, tid = threadIdx.x;
  __shared__ int cnt2[256*NK];
  #pragma unroll
  for (int kk=0;kk<NK;kk++) cnt2[tid*NK+kk]=0;
  __syncthreads();
  for (int i=tid;i<NNZT;i+=256) if (row[i]==lo) cnt2[tid*NK + ker[i]]++;
  __syncthreads();
  if (tid==0){
    int run=0;
    for (int kk=0;kk<NK;kk++){
      kptr_g[lo*10+kk]=run;
      for (int t=0;t<256;t++){ int tmp=cnt2[t*NK+kk]; cnt2[t*NK+kk]=run; run+=tmp; }
    }
    kptr_g[lo*10+9]=run;
  }
  __syncthreads();
  for (int i=tid;i<NNZT;i+=256) if (row[i]==lo){
    int kk=ker[i];
    int off=cnt2[tid*NK+kk]++;
    if (off<ROWCAP){
      int c=col[i];
      meta_g[lo*ROWCAP+off]=make_int2(((c/NLON)<<16)|(c%NLON), __float_as_int(vals[i]));
    }
  }
}

// -- x -> bf16, layout [b][lat][cquad(16)][784 pos][4 ch], wrap-padded --------
// one 8B entry per position = 4 channels -> gather needs 1 dwordx2 per nz/lane
__global__ __launch_bounds__(256) void k_xb(const float* __restrict__ x, ushort* __restrict__ xb){
  const int bid=blockIdx.x, tid=threadIdx.x;
  const int b=bid/NLAT, lat=bid-b*NLAT;
  const float* xs = x + (size_t)b*CIN*NLAT*NLON + (size_t)lat*NLON;
  ushort* xd = xb + (size_t)(b*NLAT+lat)*16*PADL*4;
  const size_t S=(size_t)NLAT*NLON;
  for (int idx=tid; idx<16*PADL; idx+=256){
    int cq=idx/PADL, j=idx-cq*PADL;
    int jj = (j<NLON)? j : j-NLON;
    const float* xc = xs + (size_t)(cq*4)*S + jj;
    uint lo32 = packbf2(xc[0], xc[S]);
    uint hi32 = packbf2(xc[2*S], xc[3*S]);
    *(uint2*)(xd + (size_t)(cq*PADL + j)*4) = make_uint2(lo32, hi32);
  }
}

// ---------------- fused gather + channel-mix main kernel ---------------------
template<int USE_XB>
__global__ __launch_bounds__(256,4) void k_main(const float* __restrict__ x, const ushort* __restrict__ xb,
    const int2* __restrict__ meta_g, const int* __restrict__ kptr_g,
    const float* __restrict__ w, const float* __restrict__ bias, float* __restrict__ out){
  const int bid=blockIdx.x, tid=threadIdx.x;
  const int lo=bid/6; const int rem=bid-lo*6;
  const int b=rem/3, pq=rem-(rem/3)*3;

  __shared__ int2  meta[ROWCAP];                 // 3072 B
  __shared__ __align__(16) ushort Ych[144*64];   // 18432 B, stride 64 (conflict-free)
  __shared__ uint  Wp[32*145];                   // 18560 B, stride 145 (banks differ per ocq)
                                                 // total 40064 B -> 4 blocks/CU

  int kp[10];
  #pragma unroll
  for (int kk=0;kk<10;kk++){ int v=kptr_g[lo*10+kk]; kp[kk]=v<ROWCAP?v:ROWCAP; }
  for (int i=tid;i<kp[9];i+=256) meta[i]=meta_g[lo*ROWCAP+i];

  const int cg=tid>>6, pl=tid&63;      // gather roles: wave id (c-quad), p-lane
  const int ocq=tid>>4, pq4=tid&15;    // stage-2 roles: oc-quad, p-quad
  const char* xb8 = (const char*)xb + (size_t)b*NLAT*16*PADL*8;

  float outacc[4][4][4];
  #pragma unroll
  for (int a=0;a<4;a++)
    #pragma unroll
    for (int b2=0;b2<4;b2++)
      #pragma unroll
      for (int c2=0;c2<4;c2++) outacc[a][b2][c2]=0.f;

  for (int chunk=0;chunk<4;chunk++){
    const int c0=chunk*16;
    __syncthreads();   // prev chunk's stage-2 done (Wp free); covers meta on iter 0
    for (int idx=tid; idx<32*144; idx+=256){
      int oc2=idx/144, ckl=idx-oc2*144;
      int cl=ckl/9, kk=ckl-cl*9;
      const float* wp = w + (oc2*2)*CKTOT + (c0+cl)*NK + kk;
      Wp[oc2*145+ckl] = packbf2(wp[0], wp[CKTOT]);
    }
    const uint cqoff = (uint)(chunk*4+cg)*(PADL*8);
    #pragma unroll
    for (int pt=0;pt<4;pt++){
      const int p0 = pq*240 + pt*64;
      float acc[4][NK];
      #pragma unroll
      for (int j=0;j<4;j++)
        #pragma unroll
        for (int kk=0;kk<NK;kk++) acc[j][kk]=0.f;

#define GBODY(M,KK) { \
      int lat=(M).x>>16, lon=(M).x&0xffff; \
      float v=__int_as_float((M).y); \
      int s=lon+p0; s=(s>=NLON)?s-NLON:s; \
      uint off=(uint)lat*(16u*PADL*8u)+cqoff+(uint)(s+pl)*8u; \
      uint2 u=*(const uint2*)(xb8+off); \
      acc[0][KK]+=v*bfu(u.x); acc[1][KK]+=v*bfh(u.x); \
      acc[2][KK]+=v*bfu(u.y); acc[3][KK]+=v*bfh(u.y); }

#define GBODYF(M,KK) { \
      int lat=(M).x>>16, lon=(M).x&0xffff; \
      float v=__int_as_float((M).y); \
      int s=lon+p0; s=(s>=NLON)?s-NLON:s; \
      int widx=s+pl; widx=(widx>=NLON)?widx-NLON:widx; \
      int base=((b*CIN + c0+cg*4)*NLAT + lat)*NLON + widx; \
      acc[0][KK]+=v*x[base]; \
      acc[1][KK]+=v*x[base+NLAT*NLON]; \
      acc[2][KK]+=v*x[base+2*NLAT*NLON]; \
      acc[3][KK]+=v*x[base+3*NLAT*NLON]; }

      #pragma unroll
      for (int kk=0;kk<NK;kk++){
        int i=kp[kk]; const int e=kp[kk+1];
        if (USE_XB){
          for (; i+1<e; i+=2){
            int2 m0=meta[i], m1=meta[i+1];
            GBODY(m0,kk); GBODY(m1,kk);
          }
          if (i<e){ int2 m0=meta[i]; GBODY(m0,kk); }
        } else {
          for (; i<e; i++){ int2 m0=meta[i]; GBODYF(m0,kk); }
        }
      }
#undef GBODY
#undef GBODYF
      __syncthreads();  // prev pt's stage-2 finished reading Ych
      #pragma unroll
      for (int j=0;j<4;j++){
        int cl = cg*4 + j;
        #pragma unroll
        for (int kk=0;kk<NK;kk++)
          Ych[(cl*NK+kk)*64 + pl] = f2bf(acc[j][kk]);
      }
      __syncthreads();  // Ych (and Wp) visible
      // ---- stage 2: out[oc][p] += W[oc][ck] * Y[ck][p], 4x4 reg blocking ----
      for (int ckl=0; ckl<144; ckl++){
        uint2 yy = *(const uint2*)&Ych[ckl*64 + pq4*4];
        uint w01 = Wp[(ocq*2)*145 + ckl];
        uint w23 = Wp[(ocq*2+1)*145 + ckl];
        float yf[4]={bfu(yy.x),bfh(yy.x),bfu(yy.y),bfh(yy.y)};
        float wf[4]={bfu(w01),bfh(w01),bfu(w23),bfh(w23)};
        #pragma unroll
        for (int jo=0;jo<4;jo++)
          #pragma unroll
          for (int jp=0;jp<4;jp++)
            outacc[pt][jo][jp] += wf[jo]*yf[jp];
      }
    }
  }
  // ---- epilogue: coalesced float4 stores + bias ----
  #pragma unroll
  for (int pt=0;pt<4;pt++){
    int pidx = pt*64 + pq4*4;
    if (pidx<240){
      #pragma unroll
      for (int jo=0;jo<4;jo++){
        int oc=ocq*4+jo;
        float bs=bias[oc];
        float4 o4 = make_float4(outacc[pt][jo][0]+bs, outacc[pt][jo][1]+bs,
                                outacc[pt][jo][2]+bs, outacc[pt][jo][3]+bs);
        *(float4*)(out + ((size_t)(b*COUT+oc)*NLAT + lo)*NLON + pq*240 + pidx) = o4;
      }
    }
  }
}

extern "C" void kernel_launch(void* const* d_in, const int* in_sizes, int n_in,
                              void* d_out, int out_size, void* d_ws, size_t ws_size,
                              hipStream_t stream){
  const float* x   =(const float*)d_in[0];
  const float* vals=(const float*)d_in[1];
  const float* w   =(const float*)d_in[2];
  const float* bias=(const float*)d_in[3];
  const int* ker=(const int*)d_in[4];
  const int* row=(const int*)d_in[5];
  const int* col=(const int*)d_in[6];
  float* out=(float*)d_out;

  const size_t META_B=(size_t)NLAT*ROWCAP*sizeof(int2);
  const size_t KPTR_B=((size_t)NLAT*10*sizeof(int)+15)&~(size_t)15;
  const size_t XB_B=(size_t)2*NLAT*16*PADL*4*sizeof(ushort);
  int2* meta_g=(int2*)d_ws;
  int*  kptr_g=(int*)((char*)d_ws+META_B);
  ushort* xb=(ushort*)((char*)d_ws+META_B+KPTR_B);
  const bool use_xb = ws_size >= META_B+KPTR_B+XB_B;

  k_csr<<<dim3(NLAT), dim3(256), 0, stream>>>(ker,row,col,vals,meta_g,kptr_g);
  if (use_xb){
    k_xb<<<dim3(2*NLAT), dim3(256), 0, stream>>>(x, xb);
    k_main<1><<<dim3(NLAT*6), dim3(256), 0, stream>>>(x,xb,meta_g,kptr_g,w,bias,out);
  } else {
    k_main<0><<<dim3(NLAT*6), dim3(256), 0, stream>>>(x,xb,meta_g,kptr_g,w,bias,out);
  }
}

// Round 4
// 2044.660 us; speedup vs baseline: 2.2491x; 1.3119x over previous
//
#include <hip/hip_runtime.h>

typedef unsigned int uint;
typedef unsigned short ushort;

#define NLAT 361
#define NLON 720
#define NNZT 65536
#define CIN 64
#define COUT 64
#define NK 9
#define PADL 784     // 720 + 64 wrap pad
#define ROWCAP 384   // max row population ~230 (15 sigma margin)
#define CKTOT 576    // CIN*NK
#define YPS 168      // Yp row stride in ushorts (336B: 16B-aligned, 8-bank spread)
#define WTS 640      // Wt row stride in ushorts (4 chunks x 160)

typedef __attribute__((ext_vector_type(8))) short short8v;   // 8 bf16 (4 VGPRs)
typedef __attribute__((ext_vector_type(4))) float f32x4;     // MFMA C/D

__device__ __forceinline__ float bfu(uint u){ return __uint_as_float(u<<16); }
__device__ __forceinline__ float bfh(uint u){ return __uint_as_float(u & 0xffff0000u); }
__device__ __forceinline__ ushort f2bf(float f){
  uint b = __float_as_uint(f);
  return (ushort)((b + 0x7fffu + ((b>>16)&1u)) >> 16);
}
__device__ __forceinline__ uint packbf2(float f0, float f1){
  uint b0 = __float_as_uint(f0), b1 = __float_as_uint(f1);
  uint r0 = (b0 + 0x7fffu + ((b0>>16)&1u)) >> 16;
  uint r1 = ((b1 + 0x7fffu + ((b1>>16)&1u)) >> 16) << 16;
  return r0 | r1;
}

// ---------------- CSR build: per-row, k-sorted, deterministic ----------------
__global__ __launch_bounds__(256) void k_csr(const int* __restrict__ ker, const int* __restrict__ row,
                                             const int* __restrict__ col, const float* __restrict__ vals,
                                             int2* __restrict__ meta_g, int* __restrict__ kptr_g){
  const int lo = blockIdx.x, tid = threadIdx.x;
  __shared__ int cnt2[256*NK];
  #pragma unroll
  for (int kk=0;kk<NK;kk++) cnt2[tid*NK+kk]=0;
  __syncthreads();
  for (int i=tid;i<NNZT;i+=256) if (row[i]==lo) cnt2[tid*NK + ker[i]]++;
  __syncthreads();
  if (tid==0){
    int run=0;
    for (int kk=0;kk<NK;kk++){
      kptr_g[lo*10+kk]=run;
      for (int t=0;t<256;t++){ int tmp=cnt2[t*NK+kk]; cnt2[t*NK+kk]=run; run+=tmp; }
    }
    kptr_g[lo*10+9]=run;
  }
  __syncthreads();
  for (int i=tid;i<NNZT;i+=256) if (row[i]==lo){
    int kk=ker[i];
    int off=cnt2[tid*NK+kk]++;
    if (off<ROWCAP){
      int c=col[i];
      meta_g[lo*ROWCAP+off]=make_int2(((c/NLON)<<16)|(c%NLON), __float_as_int(vals[i]));
    }
  }
}

// -- x -> bf16, layout [b][lat][cquad(16)][784 pos][4 ch], wrap-padded --------
__global__ __launch_bounds__(256) void k_xb(const float* __restrict__ x, ushort* __restrict__ xb){
  const int bid=blockIdx.x, tid=threadIdx.x;
  const int b=bid/NLAT, lat=bid-b*NLAT;
  const float* xs = x + (size_t)b*CIN*NLAT*NLON + (size_t)lat*NLON;
  ushort* xd = xb + (size_t)(b*NLAT+lat)*16*PADL*4;
  const size_t S=(size_t)NLAT*NLON;
  for (int idx=tid; idx<16*PADL; idx+=256){
    int cq=idx/PADL, j=idx-cq*PADL;
    int jj = (j<NLON)? j : j-NLON;
    const float* xc = xs + (size_t)(cq*4)*S + jj;
    uint lo32 = packbf2(xc[0], xc[S]);
    uint hi32 = packbf2(xc[2*S], xc[3*S]);
    *(uint2*)(xd + (size_t)(cq*PADL + j)*4) = make_uint2(lo32, hi32);
  }
}

// -- W -> bf16, Wt[oc][chunk*160 + cl*9 + kk], slots 144..159 zero ------------
__global__ __launch_bounds__(256) void k_wt(const float* __restrict__ w, ushort* __restrict__ wt){
  int idx = blockIdx.x*256 + threadIdx.x;   // grid covers 64*640
  if (idx >= COUT*WTS) return;
  int oc = idx/WTS, ckl = idx-oc*WTS;
  int chunk = ckl/160, q = ckl-chunk*160;
  ushort v = 0;
  if (q < 144) v = f2bf(w[oc*CKTOT + chunk*144 + q]);
  wt[oc*WTS + ckl] = v;
}

// ---------------- fused gather + MFMA channel-mix main kernel ----------------
template<int USE_XB>
__global__ __launch_bounds__(256,3) void k_main(const float* __restrict__ x, const ushort* __restrict__ xb,
    const int2* __restrict__ meta_g, const int* __restrict__ kptr_g,
    const ushort* __restrict__ wt, const float* __restrict__ bias, float* __restrict__ out){
  const int bid=blockIdx.x, tid=threadIdx.x;
  const int lo=bid/6; const int rem=bid-lo*6;
  const int b=rem/3, pq=rem-(rem/3)*3;

  __shared__ int2 meta[ROWCAP];                    // 3072 B
  __shared__ __align__(16) ushort Yp[64*YPS];      // 21504 B  [p=64][ck=160+pad]
                                                   // total 24576 B

  int kp[10];
  #pragma unroll
  for (int kk=0;kk<10;kk++){ int v=kptr_g[lo*10+kk]; kp[kk]=v<ROWCAP?v:ROWCAP; }
  for (int i=tid;i<kp[9];i+=256) meta[i]=meta_g[lo*ROWCAP+i];
  // zero pad rows ck 144..159 once (never rewritten)
  for (int idx=tid; idx<64*8; idx+=256){
    int p=idx>>3, j=idx&7;
    *(uint*)((char*)Yp + p*(YPS*2) + 288 + j*4) = 0;
  }
  __syncthreads();

  const int lane=tid&63, wv=tid>>6;     // wv: gather c-quad AND oc-tile
  const int l15=lane&15, kg=lane>>4;
  const char* xb8 = (const char*)xb + (size_t)b*NLAT*16*PADL*8;
  const char* wtb = (const char*)wt + ((wv*16+l15)*WTS + kg*8)*2;  // A-frag lane base
  const char* ypb = (const char*)Yp + l15*(YPS*2) + kg*16;         // B-frag lane base

  float b4[4];
  #pragma unroll
  for (int r=0;r<4;r++) b4[r]=bias[wv*16 + kg*4 + r];

  f32x4 outacc[4][4];   // [pt][ptile]
  #pragma unroll
  for (int a=0;a<4;a++)
    #pragma unroll
    for (int c2=0;c2<4;c2++) outacc[a][c2]=(f32x4)0.f;

  for (int chunk=0;chunk<4;chunk++){
    const int c0=chunk*16;
    // A-frags for this chunk: Wt[wv*16+l15][chunk*160 + ks*32 + kg*8 .. +8)
    short8v af[5];
    #pragma unroll
    for (int ks=0;ks<5;ks++)
      af[ks] = *(const short8v*)(wtb + (chunk*160 + ks*32)*2);

    const uint cqoff = (uint)(chunk*4+wv)*(PADL*8);
    #pragma unroll
    for (int pt=0;pt<4;pt++){
      const int p0 = pq*240 + pt*64;
      float acc[4][NK];
      #pragma unroll
      for (int j=0;j<4;j++)
        #pragma unroll
        for (int kk=0;kk<NK;kk++) acc[j][kk]=0.f;

#define GBODY(M,KK) { \
      int lat=(M).x>>16, lon=(M).x&0xffff; \
      float v=__int_as_float((M).y); \
      int s=lon+p0; s=(s>=NLON)?s-NLON:s; \
      uint off=(uint)lat*(16u*PADL*8u)+cqoff+(uint)(s+lane)*8u; \
      uint2 u=*(const uint2*)(xb8+off); \
      acc[0][KK]+=v*bfu(u.x); acc[1][KK]+=v*bfh(u.x); \
      acc[2][KK]+=v*bfu(u.y); acc[3][KK]+=v*bfh(u.y); }

#define GBODYF(M,KK) { \
      int lat=(M).x>>16, lon=(M).x&0xffff; \
      float v=__int_as_float((M).y); \
      int s=lon+p0; s=(s>=NLON)?s-NLON:s; \
      int widx=s+lane; widx=(widx>=NLON)?widx-NLON:widx; \
      int base=((b*CIN + c0+wv*4)*NLAT + lat)*NLON + widx; \
      acc[0][KK]+=v*x[base]; \
      acc[1][KK]+=v*x[base+NLAT*NLON]; \
      acc[2][KK]+=v*x[base+2*NLAT*NLON]; \
      acc[3][KK]+=v*x[base+3*NLAT*NLON]; }

      #pragma unroll
      for (int kk=0;kk<NK;kk++){
        int i=kp[kk]; const int e=kp[kk+1];
        if (USE_XB){
          for (; i+3<e; i+=4){
            int2 m0=meta[i], m1=meta[i+1], m2=meta[i+2], m3=meta[i+3];
            GBODY(m0,kk); GBODY(m1,kk); GBODY(m2,kk); GBODY(m3,kk);
          }
          for (; i<e; i++){ int2 m0=meta[i]; GBODY(m0,kk); }
        } else {
          for (; i<e; i++){ int2 m0=meta[i]; GBODYF(m0,kk); }
        }
      }
#undef GBODY
#undef GBODYF
      __syncthreads();  // prev pt's MFMA reads of Yp done
      // write Y transposed: Yp[p=lane][ck = wv*36 + 2*i2 + {0,1}] as bf16 pairs
      {
        char* dst = (char*)Yp + lane*(YPS*2) + wv*72;
        #pragma unroll
        for (int i2=0;i2<18;i2++){
          const int t0=2*i2, t1=2*i2+1;
          uint pr = packbf2(acc[t0/9][t0-9*(t0/9)], acc[t1/9][t1-9*(t1/9)]);
          *(uint*)(dst + i2*4) = pr;
        }
      }
      __syncthreads();  // Yp visible
      // ---- stage 2 via MFMA: out[16oc x 64p] tile per wave ----
      #pragma unroll
      for (int ptile=0;ptile<4;ptile++){
        #pragma unroll
        for (int ks=0;ks<5;ks++){
          short8v bf = *(const short8v*)(ypb + ptile*(16*YPS*2) + ks*64);
          outacc[pt][ptile] = __builtin_amdgcn_mfma_f32_16x16x32_bf16(af[ks], bf, outacc[pt][ptile], 0, 0, 0);
        }
      }
    }
  }
  // ---- epilogue: D mapping col=lane&15 (p), row=(lane>>4)*4+reg (oc) ----
  // Tiles span 256 p's but each block owns 240; the last 16 are wrap-duplicates
  // (pq<2: same values as next block's first tile; pq=2: p>=720 would be OOB).
  // MUST guard: store only pidx<240.
  #pragma unroll
  for (int pt=0;pt<4;pt++)
    #pragma unroll
    for (int ptile=0;ptile<4;ptile++){
      const int pidx = pt*64 + ptile*16;
      if (pidx < 240){
        #pragma unroll
        for (int r=0;r<4;r++){
          int oc = wv*16 + kg*4 + r;
          int p  = pq*240 + pidx + l15;
          out[((size_t)(b*COUT+oc)*NLAT + lo)*NLON + p] = outacc[pt][ptile][r] + b4[r];
        }
      }
    }
}

extern "C" void kernel_launch(void* const* d_in, const int* in_sizes, int n_in,
                              void* d_out, int out_size, void* d_ws, size_t ws_size,
                              hipStream_t stream){
  const float* x   =(const float*)d_in[0];
  const float* vals=(const float*)d_in[1];
  const float* w   =(const float*)d_in[2];
  const float* bias=(const float*)d_in[3];
  const int* ker=(const int*)d_in[4];
  const int* row=(const int*)d_in[5];
  const int* col=(const int*)d_in[6];
  float* out=(float*)d_out;

  const size_t META_B=(size_t)NLAT*ROWCAP*sizeof(int2);
  const size_t KPTR_B=((size_t)NLAT*10*sizeof(int)+15)&~(size_t)15;
  const size_t WT_B=((size_t)COUT*WTS*sizeof(ushort)+15)&~(size_t)15;
  const size_t XB_B=(size_t)2*NLAT*16*PADL*4*sizeof(ushort);
  int2* meta_g=(int2*)d_ws;
  int*  kptr_g=(int*)((char*)d_ws+META_B);
  ushort* wt=(ushort*)((char*)d_ws+META_B+KPTR_B);
  ushort* xb=(ushort*)((char*)d_ws+META_B+KPTR_B+WT_B);
  const bool use_xb = ws_size >= META_B+KPTR_B+WT_B+XB_B;

  k_csr<<<dim3(NLAT), dim3(256), 0, stream>>>(ker,row,col,vals,meta_g,kptr_g);
  k_wt <<<dim3((COUT*WTS+255)/256), dim3(256), 0, stream>>>(w, wt);
  if (use_xb){
    k_xb<<<dim3(2*NLAT), dim3(256), 0, stream>>>(x, xb);
    k_main<1><<<dim3(NLAT*6), dim3(256), 0, stream>>>(x,xb,meta_g,kptr_g,wt,bias,out);
  } else {
    k_main<0><<<dim3(NLAT*6), dim3(256), 0, stream>>>(x,xb,meta_g,kptr_g,wt,bias,out);
  }
}